// Round 11
// baseline (481.358 us; speedup 1.0000x reference)
//
#include <hip/hip_runtime.h>

#define T_STEPS 4096
#define HID 64
#define FEAT_LD 14464   // 14400 conv_out (p-major: col=p*64+oc) + 8 emb + 56 pad

typedef unsigned int uint;
typedef unsigned short ushort_t;
typedef _Float16 h2v __attribute__((ext_vector_type(2)));
typedef _Float16 v8h __attribute__((ext_vector_type(8)));
typedef float v4f __attribute__((ext_vector_type(4)));

__device__ __forceinline__ uint cvtpk(float a, float b) {
  return __builtin_bit_cast(uint, __builtin_amdgcn_cvt_pkrtz(a, b));
}
__device__ __forceinline__ uint packrelu(float a, float b) {
  return __builtin_bit_cast(
      uint, __builtin_amdgcn_cvt_pkrtz(fmaxf(a, 0.f), fmaxf(b, 0.f)));
}
__device__ __forceinline__ ushort_t hrelu(float a) {
  _Float16 h = (_Float16)fmaxf(a, 0.f);
  return __builtin_bit_cast(ushort_t, h);
}
// async global->LDS DMA, 16B/lane, LDS dest = wave-uniform base + lane*16
__device__ __forceinline__ void dma16(const _Float16* g, _Float16* l) {
  __builtin_amdgcn_global_load_lds(
      (const __attribute__((address_space(1))) void*)g,
      (__attribute__((address_space(3))) void*)l, 16, 0, 0);
}

// ---------------------------------------------------------------------------
// K0a: stage w_ih as f16, columns permuted to p-major feat layout
// ---------------------------------------------------------------------------
__global__ __launch_bounds__(256) void prep_b(const float* __restrict__ w_ih,
                                              _Float16* __restrict__ Bw) {
  int i = blockIdx.x * 256 + threadIdx.x;
  if (i >= 192 * FEAT_LD) return;
  int row = i / FEAT_LD, col = i - row * FEAT_LD;
  float v = 0.f;
  if (col < 14400) {
    int p = col >> 6, oc = col & 63;
    v = w_ih[row * 14408 + oc * 225 + p];
  } else if (col < 14408) {
    v = w_ih[row * 14408 + col];
  }
  Bw[i] = (_Float16)v;
}

// ---------------------------------------------------------------------------
// K0b: pack conv weights as MFMA fragments (unchanged).
// ---------------------------------------------------------------------------
__global__ __launch_bounds__(256) void prep_conv(const float* __restrict__ w1,
                                                 const float* __restrict__ w2,
                                                 _Float16* __restrict__ bpack1,
                                                 _Float16* __restrict__ bpack) {
  int t = blockIdx.x * 256 + threadIdx.x;  // grid 72*256 = 18432
  if (t < 2048) {
    int j = t & 7, l = (t >> 3) & 63, nf = (t >> 9) & 1, ks = t >> 10;
    int k = ks * 32 + ((l >> 4) * 8) + j;
    int cc = k & 3, kk = k >> 2;
    int oc = nf * 16 + (l & 15);
    float v = (cc < 3 && kk < 9) ? w1[oc * 27 + cc * 9 + kk] : 0.f;
    bpack1[t] = (_Float16)v;
  }
  if (t < 18432) {
    int j = t & 7, l = (t >> 3) & 63, nf = (t >> 9) & 3, kk = t >> 11;
    int oc = nf * 16 + (l & 15), ic = (l >> 4) * 8 + j;
    bpack[t] = (_Float16)w2[oc * 288 + ic * 9 + kk];
  }
}

// ---------------------------------------------------------------------------
// K0c: image fp32 -> f16/255 in [img][row][px][4ch] layout (DMA-ready).
// Memory-bound (~55us total); enables zero-VALU async staging in conv.
// ---------------------------------------------------------------------------
__global__ __launch_bounds__(256) void prep_img(const float* __restrict__ image,
                                                _Float16* __restrict__ imgH,
                                                int imgBase, int nImg) {
  int i = blockIdx.x * 256 + threadIdx.x;
  if (i >= nImg * 1024) return;
  int im = i >> 10, g = i & 1023;  // group = 4 pixels = 12 floats -> 2 uint4
  const float* s0 = image + (size_t)(imgBase + im) * 12288 + g * 12;
  const float kn = 1.f / 255.f;
  float4 A = *(const float4*)s0, B = *(const float4*)(s0 + 4),
         C = *(const float4*)(s0 + 8);
  uint4 u0, u1;
  u0.x = cvtpk(A.x * kn, A.y * kn);
  u0.y = cvtpk(A.z * kn, 0.f);
  u0.z = cvtpk(A.w * kn, B.x * kn);
  u0.w = cvtpk(B.y * kn, 0.f);
  u1.x = cvtpk(B.z * kn, B.w * kn);
  u1.y = cvtpk(C.x * kn, 0.f);
  u1.z = cvtpk(C.y * kn, C.z * kn);
  u1.w = cvtpk(C.w * kn, 0.f);
  _Float16* d = imgH + (size_t)im * 16384 + g * 16;
  *(uint4*)d = u0;
  *(uint4*)(d + 8) = u1;
}

// ---------------------------------------------------------------------------
// K1: WHOLE-IMAGE block, 512 threads, quarters pipelined via global_load_lds
// double-buffer (R10's pipeline WITHOUT the register staging that spilled:
// R10 WRITE_SIZE 304MB = 177B/thread scratch = La/Lb/Lc x4 iters).
//   iter q: {issue DMA(q+1 -> img_c[buf^1])} -> conv1(q) -> bar1 ->
//           conv2(q) -> out_s -> vmcnt(0) -> bar2 -> feat-write(q).
// DMA latency (~300-900cyc) hides under conv1+conv2 (~1500cyc).
// Weights pinned in VGPR via asm anchors (verified R10: VGPR=64 incl wb).
// c1 parity-split + (pin>>2)&3 slot swizzle (2-way banks, verified R8).
// Hazard ledger: c1: conv2(q) reads < bar2(q) < conv1(q+1) writes.
//   img_c[buf^1]: DMA issued iter q, vmcnt+bar2(q) publishes, conv1(q+1) reads;
//     old readers of buf^1 (conv1(q-1)) finished before bar1(q-1) < issue.
//   out_s: conv2(q) writes < bar2(q) < feat-read(q) < bar1(q+1) < conv2(q+1).
// LDS: img 2x10KB + c1 18KB + out 8KB = 46.5KB -> 3 blocks/CU.
// ---------------------------------------------------------------------------
__global__ __launch_bounds__(512, 4) void conv_kernel(
    const _Float16* __restrict__ imgH, const int* __restrict__ dir,
    const _Float16* __restrict__ bpack1, const float* __restrict__ b1,
    const _Float16* __restrict__ bpack, const float* __restrict__ b2,
    const float* __restrict__ emb, _Float16* __restrict__ feat, int imgBase) {
  __shared__ __align__(16) _Float16 img_c[2][5120];  // 2 x 10KB (19 rows + slack)
  __shared__ __align__(16) char c1_s[288 * 64];      // parity-split 18KB
  __shared__ __align__(16) ushort_t out_s[64 * 64];  // [pos][oc] 8KB

  const int tid = threadIdx.x;
  const int wid = tid >> 6, lane = tid & 63;
  const int lrow = lane & 15, lq = lane >> 4;
  const int img = imgBase + blockIdx.x;
  const _Float16* ib = imgH + (size_t)blockIdx.x * 16384;  // this image, f16
  _Float16* fr = feat + (size_t)blockIdx.x * FEAT_LD;

  // --- PRELOAD + PIN conv2 weight column (nf): 9 v8h = 36 VGPR ---
  const int nf = wid & 3, mh = wid >> 2;
  v8h wb[9];
#pragma unroll
  for (int kk = 0; kk < 9; ++kk) {
    uint4 t = *(const uint4*)(bpack + ((size_t)(kk * 4 + nf) * 64 + lane) * 8);
    asm volatile("" : "+v"(t.x), "+v"(t.y), "+v"(t.z), "+v"(t.w));
    wb[kk] = __builtin_bit_cast(v8h, t);
  }
  const float b2v = b2[nf * 16 + lrow];

  // conv1 W-frags (A operand) + per-row bias quads
  v8h bw1[2][2];
#pragma unroll
  for (int f = 0; f < 2; ++f)
#pragma unroll
    for (int ks = 0; ks < 2; ++ks)
      bw1[f][ks] =
          *(const v8h*)(bpack1 + ((size_t)(ks * 2 + f) * 64 + lane) * 8);
  const float4 b1q0 = *(const float4*)(b1 + lq * 4);
  const float4 b1q1 = *(const float4*)(b1 + 16 + lq * 4);

  // per-lane pixel offsets for conv1 im2col frags
  const int kk0 = 2 * lq, kk1 = 2 * lq + 1;
  const int off0 = ((kk0 / 3) * 64 + (kk0 - 3 * (kk0 / 3))) * 4;
  const int off1 = ((kk1 / 3) * 64 + (kk1 - 3 * (kk1 / 3))) * 4;
  const int off8 = (2 * 64 + 2) * 4;  // kk=8 pixel

  if (tid < 64) {  // emb + zero pad (cols 14400..14463)
    int d = dir[img];
    fr[14400 + tid] = (tid < 8) ? (_Float16)emb[d * 8 + tid] : (_Float16)0.f;
  }

  // --- prologue: DMA quarter 0 (rows 0..19 = 10 x 1KB issues) ---
  for (int j = wid; j < 10; j += 8)
    dma16(ib + j * 512 + lane * 8, img_c[0] + j * 512);
  asm volatile("s_waitcnt vmcnt(0)" ::: "memory");
  __syncthreads();

  int buf = 0;
  for (int q = 0; q < 4; ++q) {
    const int q3 = (q == 3);
    const int nvalid = q3 ? 217 : 279;
    const int npos = q3 ? 45 : 60;

    // --- issue DMA for next quarter (async; lands before bar2) ---
    if (q < 3) {
      const _Float16* qs = ib + (q + 1) * 4096;  // quarter base (halves)
      const int nIss = (q + 1 < 3) ? 10 : 8;     // 19 rows / 16 rows (q=3)
      for (int j = wid; j < nIss; j += 8)
        dma16(qs + j * 512 + lane * 8, img_c[buf ^ 1] + j * 512);
    }

    // ===== conv1(q): 18 pos-frags over 8 waves, K=64, C cols = pos ========
#pragma unroll
    for (int f = 0; f < 3; ++f) {
      const int mf = wid + 8 * f;
      if (mf >= 18) break;
      const int pin = mf * 16 + lrow;
      const int pv = (pin < 279) ? pin : 278;
      const int ly = pv / 31, lx = pv - 31 * ly;
      const _Float16* pb = img_c[buf] + ((2 * ly) * 64 + 2 * lx) * 4;
      uint2 p0 = *(const uint2*)(pb + off0);
      uint2 p1 = *(const uint2*)(pb + off1);
      uint2 p8 = *(const uint2*)(pb + off8);
      uint4 u0;
      u0.x = p0.x; u0.y = p0.y; u0.z = p1.x; u0.w = p1.y;
      uint4 u1;
      u1.x = (lq == 0) ? p8.x : 0u;
      u1.y = (lq == 0) ? p8.y : 0u;
      u1.z = 0u; u1.w = 0u;
      v8h a0 = __builtin_bit_cast(v8h, u0);
      v8h a1 = __builtin_bit_cast(v8h, u1);
      v4f ac0 = __builtin_bit_cast(v4f, b1q0);
      v4f ac1 = __builtin_bit_cast(v4f, b1q1);
      ac0 = __builtin_amdgcn_mfma_f32_16x16x32_f16(bw1[0][0], a0, ac0, 0, 0, 0);
      ac0 = __builtin_amdgcn_mfma_f32_16x16x32_f16(bw1[0][1], a1, ac0, 0, 0, 0);
      ac1 = __builtin_amdgcn_mfma_f32_16x16x32_f16(bw1[1][0], a0, ac1, 0, 0, 0);
      ac1 = __builtin_amdgcn_mfma_f32_16x16x32_f16(bw1[1][1], a1, ac1, 0, 0, 0);
      if (pin < nvalid) {
        char* base = c1_s + ((pin & 1) * 144 + (pin >> 1)) * 64;
        const int sw = (pin >> 2) & 3;  // 8-row period -> 2-way banks
        uint2 u;
        u.x = packrelu(ac0[0], ac0[1]);
        u.y = packrelu(ac0[2], ac0[3]);
        *(uint2*)(base + ((((lq >> 1) ^ sw) << 4) + (lq & 1) * 8)) = u;
        u.x = packrelu(ac1[0], ac1[1]);
        u.y = packrelu(ac1[2], ac1[3]);
        *(uint2*)(base + ((((2 + (lq >> 1)) ^ sw) << 4) + (lq & 1) * 8)) = u;
      }
    }
    __syncthreads();  // bar1: c1 ready; feat-write(q-1) done block-wide

    // ===== conv2(q): pure LDS+MFMA (weights pinned in regs) ===============
    int abase[2];
#pragma unroll
    for (int i = 0; i < 2; ++i) {
      int pos = (2 * mh + i) * 16 + lrow;
      int pv2 = (pos < npos) ? pos : 0;
      int oy = pv2 / 15, ox = pv2 - 15 * oy;
      abase[i] = (2 * oy) * 31 + 2 * ox;
    }
    v4f acc[2];
    acc[0] = (v4f){b2v, b2v, b2v, b2v};
    acc[1] = acc[0];
#pragma unroll
    for (int kk = 0; kk < 9; ++kk) {
      const int dd = (kk / 3) * 31 + (kk - 3 * (kk / 3));
#pragma unroll
      for (int i = 0; i < 2; ++i) {
        const int pin = abase[i] + dd;
        const int sw = (pin >> 2) & 3;
        const char* base = c1_s + ((pin & 1) * 144 + (pin >> 1)) * 64;
        v8h af = *(const v8h*)(base + ((lq ^ sw) << 4));
        acc[i] =
            __builtin_amdgcn_mfma_f32_16x16x32_f16(af, wb[kk], acc[i], 0, 0, 0);
      }
    }
    // out_s [pos][oc] with oc-slot XOR (bank spread on C-stores)
#pragma unroll
    for (int i = 0; i < 2; ++i) {
      int oc = nf * 16 + lrow;
#pragma unroll
      for (int qq = 0; qq < 4; ++qq) {
        int p = (2 * mh + i) * 16 + lq * 4 + qq;
        out_s[p * 64 + (oc ^ ((p & 3) << 4))] = hrelu(acc[i][qq]);
      }
    }
    asm volatile("s_waitcnt vmcnt(0)" ::: "memory");  // next-quarter DMA done
    __syncthreads();  // bar2: out_s ready, img_c[buf^1] published

    // feat write(q): dense p-major chunk (overlaps conv1(q+1) on other waves)
    {
      uint2* fr2 = (uint2*)fr + 16 * (60 * q);
      const int nj = npos * 16;
      for (int j = tid; j < nj; j += 512) {
        int p = j >> 4, slot = j & 15;
        uint2 v =
            *(const uint2*)(out_s + p * 64 + ((slot << 2) ^ ((p & 3) << 4)));
        fr2[j] = v;
      }
    }
    buf ^= 1;
  }
}

// ---------------------------------------------------------------------------
// K2: gxp partials = feat @ Bw^T  (MFMA f16; BM=64, BN=192, runtime split-K).
// Grid is always 256 blocks: splitk = 16384/CH, mt = CH/64.
// gxp layout: [sk][row-in-chunk][192].
// ---------------------------------------------------------------------------
__global__ __launch_bounds__(256, 2) void gemm_kernel(
    const _Float16* __restrict__ feat, const _Float16* __restrict__ Bw,
    float* __restrict__ gxp, int mt, int splitk) {
  __shared__ __align__(16) _Float16 As[2][64 * 64];
  __shared__ __align__(16) _Float16 Bs[2][192 * 64];
  const int tid = threadIdx.x;
  const int w = tid >> 6, lane = tid & 63;
  const int lrow = lane & 15, lq = lane >> 4;

  // bijective xcd-contiguous swizzle (m204); nwg = mt*splitk = 256
  const int nwg = mt * splitk;
  const int q = nwg >> 3, r = nwg & 7;
  const int xcd = blockIdx.x & 7, pos = blockIdx.x >> 3;
  const int wg = (xcd < r ? xcd * (q + 1) : r * (q + 1) + (xcd - r) * q) + pos;
  const int sk = wg / mt, m = wg - sk * mt;
  const int bm = m * 64;
  const int ks0 = (sk * 226) / splitk, ks1 = ((sk + 1) * 226) / splitk;
  const int rows = mt * 64;

  int rowA[2], kcA[2], offA[2], rowB[6], kcB[6], offB[6];
#pragma unroll
  for (int i = 0; i < 2; ++i) {
    int s = w * 128 + i * 64 + lane;
    rowA[i] = s >> 3;
    kcA[i] = s & 7;
    offA[i] = rowA[i] * 128 + ((kcA[i] ^ (rowA[i] & 7)) << 4);
  }
#pragma unroll
  for (int i = 0; i < 6; ++i) {
    int s = w * 384 + i * 64 + lane;
    rowB[i] = s >> 3;
    kcB[i] = s & 7;
    offB[i] = rowB[i] * 128 + ((kcB[i] ^ (rowB[i] & 7)) << 4);
  }

  uint4 ta[2], tb[6];
  {
    int kb = ks0 * 64;
#pragma unroll
    for (int i = 0; i < 2; ++i)
      ta[i] = *(const uint4*)(feat + (size_t)(bm + rowA[i]) * FEAT_LD + kb +
                              kcA[i] * 8);
#pragma unroll
    for (int i = 0; i < 6; ++i)
      tb[i] = *(const uint4*)(Bw + (size_t)rowB[i] * FEAT_LD + kb + kcB[i] * 8);
#pragma unroll
    for (int i = 0; i < 2; ++i) *(uint4*)((char*)As[0] + offA[i]) = ta[i];
#pragma unroll
    for (int i = 0; i < 6; ++i) *(uint4*)((char*)Bs[0] + offB[i]) = tb[i];
  }
  __syncthreads();

  v4f acc[4][3] = {};
  for (int ks = ks0; ks < ks1; ++ks) {
    const int cur = (ks - ks0) & 1;
    const bool more = (ks + 1 < ks1);
    if (more) {
      int kb = (ks + 1) * 64;
#pragma unroll
      for (int i = 0; i < 2; ++i)
        ta[i] = *(const uint4*)(feat + (size_t)(bm + rowA[i]) * FEAT_LD + kb +
                                kcA[i] * 8);
#pragma unroll
      for (int i = 0; i < 6; ++i)
        tb[i] =
            *(const uint4*)(Bw + (size_t)rowB[i] * FEAT_LD + kb + kcB[i] * 8);
    }
    const char* Ab = (const char*)As[cur];
    const char* Bb = (const char*)Bs[cur];
#pragma unroll
    for (int ksub = 0; ksub < 2; ++ksub) {
      int s0 = ksub * 4 + lq;
      v8h afr[4];
#pragma unroll
      for (int mf = 0; mf < 4; ++mf) {
        int row = mf * 16 + lrow;
        afr[mf] = *(const v8h*)(Ab + row * 128 + ((s0 ^ (row & 7)) << 4));
      }
#pragma unroll
      for (int nfi = 0; nfi < 3; ++nfi) {
        int col = (w * 3 + nfi) * 16 + lrow;
        v8h bfr = *(const v8h*)(Bb + col * 128 + ((s0 ^ (col & 7)) << 4));
#pragma unroll
        for (int mf = 0; mf < 4; ++mf)
          acc[mf][nfi] = __builtin_amdgcn_mfma_f32_16x16x32_f16(
              afr[mf], bfr, acc[mf][nfi], 0, 0, 0);
      }
    }
    if (more) {
      char* An = (char*)As[cur ^ 1];
      char* Bn = (char*)Bs[cur ^ 1];
#pragma unroll
      for (int i = 0; i < 2; ++i) *(uint4*)(An + offA[i]) = ta[i];
#pragma unroll
      for (int i = 0; i < 6; ++i) *(uint4*)(Bn + offB[i]) = tb[i];
    }
    __syncthreads();
  }
  const size_t obase = (size_t)sk * rows;
#pragma unroll
  for (int mf = 0; mf < 4; ++mf) {
#pragma unroll
    for (int nfi = 0; nfi < 3; ++nfi) {
      int col = (w * 3 + nfi) * 16 + lrow;
#pragma unroll
      for (int qq = 0; qq < 4; ++qq) {
        int rowm = bm + mf * 16 + lq * 4 + qq;
        gxp[(obase + rowm) * 192 + col] = acc[mf][nfi][qq];
      }
    }
  }
}

// ---------------------------------------------------------------------------
// K2b: gx[rowBase + r] = sum_sk gxp[sk][r] + b_ih  (per chunk)
// ---------------------------------------------------------------------------
__global__ __launch_bounds__(256) void reduce_gx(const float* __restrict__ gxp,
                                                 const float* __restrict__ b_ih,
                                                 float* __restrict__ gx,
                                                 int rowBase, int rows,
                                                 int splitk) {
  int t = blockIdx.x * 256 + threadIdx.x;
  if (t >= rows * 192) return;
  int col = t - (t / 192) * 192;
  float s = b_ih[col];
  for (int k = 0; k < splitk; ++k) s += gxp[(size_t)k * rows * 192 + t];
  gx[(size_t)rowBase * 192 + t] = s;
}

// ---------------------------------------------------------------------------
// K3: chunked-parallel GRU scan. C=8, W=152 -> 512 blocks (2/CU), <=160
// steps. rho^152 <= 4.1e-4 @ rho=.95.
// ---------------------------------------------------------------------------
__global__ __launch_bounds__(192) void scan_kernel(
    const float* __restrict__ gx, const float* __restrict__ w_hh,
    const float* __restrict__ b_hh, float* __restrict__ hs, int C, int W) {
  __shared__ __align__(16) float h_s[64];
  __shared__ float r_s[64], z_s[64];
  const int tid = threadIdx.x;
  const int g = tid >> 6, j = tid & 63;
  const int b = blockIdx.x;
  const int tstore = b * C;
  const int t0 = max(0, tstore - W);
  const int t1 = tstore + C;

  float w[64];
#pragma unroll
  for (int k4 = 0; k4 < 16; ++k4) {
    float4 v = *(const float4*)(w_hh + tid * 64 + k4 * 4);
    w[4 * k4 + 0] = v.x;
    w[4 * k4 + 1] = v.y;
    w[4 * k4 + 2] = v.z;
    w[4 * k4 + 3] = v.w;
  }
  const float bh = b_hh[tid];
  if (tid < 64) h_s[tid] = 0.f;
  __syncthreads();

  float gxv = gx[(size_t)t0 * 192 + tid];
  for (int t = t0; t < t1; ++t) {
    int tn = (t + 1 < T_STEPS) ? t + 1 : T_STEPS - 1;
    float gxn = gx[(size_t)tn * 192 + tid];
    float gacc0 = bh, gacc1 = 0.f, gacc2 = 0.f, gacc3 = 0.f;
#pragma unroll
    for (int k4 = 0; k4 < 4; ++k4) {
      float4 hA = *(const float4*)(h_s + 0 + k4 * 4);
      float4 hB = *(const float4*)(h_s + 16 + k4 * 4);
      float4 hC = *(const float4*)(h_s + 32 + k4 * 4);
      float4 hD = *(const float4*)(h_s + 48 + k4 * 4);
      gacc0 = fmaf(w[0 + 4 * k4], hA.x, gacc0);
      gacc0 = fmaf(w[1 + 4 * k4], hA.y, gacc0);
      gacc0 = fmaf(w[2 + 4 * k4], hA.z, gacc0);
      gacc0 = fmaf(w[3 + 4 * k4], hA.w, gacc0);
      gacc1 = fmaf(w[16 + 4 * k4], hB.x, gacc1);
      gacc1 = fmaf(w[17 + 4 * k4], hB.y, gacc1);
      gacc1 = fmaf(w[18 + 4 * k4], hB.z, gacc1);
      gacc1 = fmaf(w[19 + 4 * k4], hB.w, gacc1);
      gacc2 = fmaf(w[32 + 4 * k4], hC.x, gacc2);
      gacc2 = fmaf(w[33 + 4 * k4], hC.y, gacc2);
      gacc2 = fmaf(w[34 + 4 * k4], hC.z, gacc2);
      gacc2 = fmaf(w[35 + 4 * k4], hC.w, gacc2);
      gacc3 = fmaf(w[48 + 4 * k4], hD.x, gacc3);
      gacc3 = fmaf(w[49 + 4 * k4], hD.y, gacc3);
      gacc3 = fmaf(w[50 + 4 * k4], hD.z, gacc3);
      gacc3 = fmaf(w[51 + 4 * k4], hD.w, gacc3);
    }
    float gh = (gacc0 + gacc1) + (gacc2 + gacc3);
    if (g == 0)
      r_s[j] = 1.f / (1.f + __expf(-(gxv + gh)));
    else if (g == 1)
      z_s[j] = 1.f / (1.f + __expf(-(gxv + gh)));
    __syncthreads();
    if (g == 2) {
      float r = r_s[j], z = z_s[j];
      float x = gxv + r * gh;
      float x2 = fminf(fmaxf(2.f * x, -30.f), 30.f);
      float e = __expf(x2);
      float n = (e - 1.f) / (e + 1.f);
      float hn = (1.f - z) * n + z * h_s[j];
      h_s[j] = hn;
      if (t >= tstore) hs[(size_t)t * 64 + j] = hn;
    }
    __syncthreads();
    gxv = gxn;
  }
}

// ---------------------------------------------------------------------------
// K4: actor/critic heads + softmax. Thread per timestep.
// ---------------------------------------------------------------------------
__global__ __launch_bounds__(256) void head_kernel(
    const float* __restrict__ hs, const float* __restrict__ aw,
    const float* __restrict__ ab, const float* __restrict__ cw,
    const float* __restrict__ cb, float* __restrict__ out) {
  int t = blockIdx.x * 256 + threadIdx.x;
  if (t >= T_STEPS) return;
  float h[64];
#pragma unroll
  for (int i = 0; i < 16; ++i) {
    float4 v = *(const float4*)(hs + (size_t)t * 64 + 4 * i);
    h[4 * i + 0] = v.x;
    h[4 * i + 1] = v.y;
    h[4 * i + 2] = v.z;
    h[4 * i + 3] = v.w;
  }
  float lg[7];
#pragma unroll
  for (int o = 0; o < 7; ++o) {
    float a = ab[o];
#pragma unroll
    for (int jj = 0; jj < 64; ++jj) a = fmaf(aw[o * 64 + jj], h[jj], a);
    lg[o] = a;
  }
  float v = cb[0];
#pragma unroll
  for (int jj = 0; jj < 64; ++jj) v = fmaf(cw[jj], h[jj], v);
  float m = lg[0];
#pragma unroll
  for (int o = 1; o < 7; ++o) m = fmaxf(m, lg[o]);
  float e[7], s = 0.f;
#pragma unroll
  for (int o = 0; o < 7; ++o) {
    e[o] = __expf(lg[o] - m);
    s += e[o];
  }
  float inv = 1.f / s;
#pragma unroll
  for (int o = 0; o < 7; ++o) out[(size_t)t * 7 + o] = e[o] * inv;
  out[(size_t)T_STEPS * 7 + t] = v;
}

// ---------------------------------------------------------------------------
extern "C" void kernel_launch(void* const* d_in, const int* in_sizes, int n_in,
                              void* d_out, int out_size, void* d_ws,
                              size_t ws_size, hipStream_t stream) {
  const float* image = (const float*)d_in[0];
  const int* dir = (const int*)d_in[1];
  const float* w1 = (const float*)d_in[2];
  const float* b1 = (const float*)d_in[3];
  const float* w2 = (const float*)d_in[4];
  const float* b2 = (const float*)d_in[5];
  const float* emb = (const float*)d_in[6];
  const float* w_ih = (const float*)d_in[7];
  const float* b_ih = (const float*)d_in[8];
  const float* w_hh = (const float*)d_in[9];
  const float* b_hh = (const float*)d_in[10];
  const float* aw = (const float*)d_in[11];
  const float* ab = (const float*)d_in[12];
  const float* cw = (const float*)d_in[13];
  const float* cb = (const float*)d_in[14];
  float* out = (float*)d_out;

  const size_t bp1Bytes = 4096;        // conv1 W frags
  const size_t bpackBytes = 18432 * 2; // conv2 B frags
  const size_t bBytes = (size_t)192 * FEAT_LD * 2;
  const size_t gxpBytes = (size_t)16384 * 192 * 4;  // splitk*CH = 16384 const
  const size_t gxBytes = (size_t)T_STEPS * 192 * 4;
  const size_t hsBytes = (size_t)T_STEPS * 64 * 4;
  const size_t fixed =
      bp1Bytes + bpackBytes + bBytes + gxpBytes + gxBytes + hsBytes;
  const size_t perImg = (size_t)FEAT_LD * 2 + 32768;  // feat row + imgH image
  int CH = 4096;
  while (CH > 256 && fixed + (size_t)CH * perImg + 1024 > ws_size) CH >>= 1;
  const int SK = 16384 / CH;  // gemm grid = (CH/64)*SK = 256 always

  char* p = (char*)d_ws;
  _Float16* bpack1 = (_Float16*)p;
  p += bp1Bytes;
  _Float16* bpack = (_Float16*)p;
  p += bpackBytes;
  _Float16* Bw = (_Float16*)p;
  p += bBytes;
  float* gxp = (float*)p;
  p += gxpBytes;
  float* gx = (float*)p;
  p += gxBytes;
  float* hs = (float*)p;
  p += hsBytes;
  _Float16* featBuf = (_Float16*)p;
  p += (size_t)CH * FEAT_LD * 2;
  _Float16* imgH = (_Float16*)p;

  prep_conv<<<72, 256, 0, stream>>>(w1, w2, bpack1, bpack);
  prep_b<<<(192 * FEAT_LD + 255) / 256, 256, 0, stream>>>(w_ih, Bw);
  for (int c = 0; c < T_STEPS; c += CH) {
    prep_img<<<(CH * 1024 + 255) / 256, 256, 0, stream>>>(image, imgH, c, CH);
    conv_kernel<<<CH, 512, 0, stream>>>(imgH, dir, bpack1, b1, bpack, b2, emb,
                                        featBuf, c);
    gemm_kernel<<<256, 256, 0, stream>>>(featBuf, Bw, gxp, CH / 64, SK);
    reduce_gx<<<(CH * 192 + 255) / 256, 256, 0, stream>>>(gxp, b_ih, gx, c, CH,
                                                          SK);
  }
  scan_kernel<<<512, 192, 0, stream>>>(gx, w_hh, b_hh, hs, 8, 152);
  head_kernel<<<(T_STEPS + 255) / 256, 256, 0, stream>>>(hs, aw, ab, cw, cb,
                                                         out);
}

// Round 12
// 408.549 us; speedup vs baseline: 1.1782x; 1.1782x over previous
//
#include <hip/hip_runtime.h>

#define T_STEPS 4096
#define HID 64
#define FEAT_LD 14464   // 14400 conv_out (p-major: col=p*64+oc) + 8 emb + 56 pad
#define SPLITK 8

typedef unsigned int uint;
typedef unsigned short ushort_t;
typedef _Float16 h2v __attribute__((ext_vector_type(2)));
typedef _Float16 v8h __attribute__((ext_vector_type(8)));
typedef float v4f __attribute__((ext_vector_type(4)));

__device__ __forceinline__ uint cvtpk(float a, float b) {
  return __builtin_bit_cast(uint, __builtin_amdgcn_cvt_pkrtz(a, b));
}
__device__ __forceinline__ uint packrelu(float a, float b) {
  return __builtin_bit_cast(
      uint, __builtin_amdgcn_cvt_pkrtz(fmaxf(a, 0.f), fmaxf(b, 0.f)));
}
__device__ __forceinline__ ushort_t hrelu(float a) {
  _Float16 h = (_Float16)fmaxf(a, 0.f);
  return __builtin_bit_cast(ushort_t, h);
}

// ---------------------------------------------------------------------------
// K0a: stage w_ih as f16 with columns PERMUTED to the p-major feat layout:
//   feat col (new) = p*64 + oc  <->  w_ih col (orig) = oc*225 + p
// ---------------------------------------------------------------------------
__global__ __launch_bounds__(256) void prep_b(const float* __restrict__ w_ih,
                                              _Float16* __restrict__ Bw) {
  int i = blockIdx.x * 256 + threadIdx.x;
  if (i >= 192 * FEAT_LD) return;
  int row = i / FEAT_LD, col = i - row * FEAT_LD;
  float v = 0.f;
  if (col < 14400) {
    int p = col >> 6, oc = col & 63;
    v = w_ih[row * 14408 + oc * 225 + p];
  } else if (col < 14408) {
    v = w_ih[row * 14408 + col];  // emb columns keep their position
  }
  Bw[i] = (_Float16)v;
}

// ---------------------------------------------------------------------------
// K0b: pack conv weights as MFMA fragments (unchanged).
// ---------------------------------------------------------------------------
__global__ __launch_bounds__(256) void prep_conv(const float* __restrict__ w1,
                                                 const float* __restrict__ w2,
                                                 _Float16* __restrict__ bpack1,
                                                 _Float16* __restrict__ bpack) {
  int t = blockIdx.x * 256 + threadIdx.x;  // grid 72*256 = 18432
  if (t < 2048) {
    int j = t & 7, l = (t >> 3) & 63, nf = (t >> 9) & 1, ks = t >> 10;
    int k = ks * 32 + ((l >> 4) * 8) + j;
    int cc = k & 3, kk = k >> 2;
    int oc = nf * 16 + (l & 15);
    float v = (cc < 3 && kk < 9) ? w1[oc * 27 + cc * 9 + kk] : 0.f;
    bpack1[t] = (_Float16)v;
  }
  if (t < 18432) {
    int j = t & 7, l = (t >> 3) & 63, nf = (t >> 9) & 3, kk = t >> 11;
    int oc = nf * 16 + (l & 15), ic = (l >> 4) * 8 + j;
    bpack[t] = (_Float16)w2[oc * 288 + ic * 9 + kk];
  }
}

// ---------------------------------------------------------------------------
// K1: quarter-image conv block (R8 structure — best verified), 512 threads.
// __launch_bounds__(512, 2): VGPR cap 256 so the asm-pinned conv2 weight
//   column (wb[9] = 36 VGPR) + bw1 + addressing (~100 total) fits WITHOUT
//   spilling. R10/R11 lesson: at (512,4)+47KB LDS the allocator targeted
//   6 waves/SIMD (85-VGPR budget), chose 64, and spilled the pinned regs
//   to scratch (WRITE_SIZE 220-304MB). Occupancy is proven decorrelated
//   with conv duration (R6-R9: 42-81% occ, dur flat), so trading waves for
//   a spill-free pin is the right direction.
// Wave roles: nf = wid&3 (ONE conv2 oc-frag per wave, weights in regs),
//   conv2 m-frags {2*(wid>>2), 2*(wid>>2)+1}. conv2 = pure LDS+MFMA.
// c1 parity-split: base=((pin&1)*144+(pin>>1))*64, slot swizzle (pin>>2)&3
//   (2-way banks, verified R8: conflicts 7.6e6). Same map write & read.
// Epilogue: out_s [pos][oc] (oc-slot XOR), dense p-major feat chunk
//   (verified R8: WRITE_SIZE == feat bytes exactly).
// ---------------------------------------------------------------------------
__global__ __launch_bounds__(512, 2) void conv_kernel(
    const float* __restrict__ image, const int* __restrict__ dir,
    const _Float16* __restrict__ bpack1, const float* __restrict__ b1,
    const _Float16* __restrict__ bpack, const float* __restrict__ b2,
    const float* __restrict__ emb, _Float16* __restrict__ feat, int imgBase) {
  __shared__ __align__(16) _Float16 img_s[1216 * 4];  // 19 rows x 64 px x 4ch
  __shared__ __align__(16) char c1_s[288 * 64];       // parity-split

  ushort_t* out_s = (ushort_t*)img_s;  // epilogue overlay [64 pos][64 oc]

  const int tid = threadIdx.x;
  const int wid = tid >> 6, lane = tid & 63;
  const int lrow = lane & 15, lq = lane >> 4;
  const int qh = blockIdx.x;
  const int img = imgBase + blockIdx.y;
  const int q3 = (qh == 3);
  const int nrows = q3 ? 16 : 19;    // img rows staged
  const int nvalid = q3 ? 217 : 279; // valid c1 local pins
  const int npos = q3 ? 45 : 60;     // conv2 out positions
  const float* ip = image + (size_t)img * 12288 + (size_t)qh * 16 * 192;
  _Float16* fr = feat + (size_t)blockIdx.y * FEAT_LD;

  // --- PRELOAD + PIN conv2 weight column (nf): 9 v8h = 36 VGPR.
  // asm anchors prevent the sink-into-loop that R9 exhibited; (512,2)'s
  // 256-VGPR cap prevents the spill that R10/R11 exhibited.
  const int nf = wid & 3, mh = wid >> 2;
  v8h wb[9];
#pragma unroll
  for (int kk = 0; kk < 9; ++kk) {
    uint4 t = *(const uint4*)(bpack + ((size_t)(kk * 4 + nf) * 64 + lane) * 8);
    asm volatile("" : "+v"(t.x), "+v"(t.y), "+v"(t.z), "+v"(t.w));
    wb[kk] = __builtin_bit_cast(v8h, t);
  }
  const float b2v = b2[nf * 16 + lrow];

  // --- stage image rows: group = 4 pixels (12 floats -> 2 uint4) ---
  const float kn = 1.f / 255.f;
  const int ng = nrows * 16;
  for (int g = tid; g < ng; g += 512) {
    const float* s0 = ip + g * 12;
    float4 A = *(const float4*)s0, B = *(const float4*)(s0 + 4),
           C = *(const float4*)(s0 + 8);
    uint4 u0, u1;
    u0.x = cvtpk(A.x * kn, A.y * kn);
    u0.y = cvtpk(A.z * kn, 0.f);
    u0.z = cvtpk(A.w * kn, B.x * kn);
    u0.w = cvtpk(B.y * kn, 0.f);
    u1.x = cvtpk(B.z * kn, B.w * kn);
    u1.y = cvtpk(C.x * kn, 0.f);
    u1.z = cvtpk(C.y * kn, C.z * kn);
    u1.w = cvtpk(C.w * kn, 0.f);
    *(uint4*)(img_s + g * 16) = u0;
    *(uint4*)(img_s + g * 16 + 8) = u1;
  }
  if (qh == 0 && tid < 64) {  // emb + zero pad (cols 14400..14463)
    int d = dir[img];
    fr[14400 + tid] = (tid < 8) ? (_Float16)emb[d * 8 + tid] : (_Float16)0.f;
  }

  // conv1 W-frags (A operand) + per-row bias quads
  v8h bw1[2][2];
#pragma unroll
  for (int f = 0; f < 2; ++f)
#pragma unroll
    for (int ks = 0; ks < 2; ++ks)
      bw1[f][ks] =
          *(const v8h*)(bpack1 + ((size_t)(ks * 2 + f) * 64 + lane) * 8);
  const float4 b1q0 = *(const float4*)(b1 + lq * 4);
  const float4 b1q1 = *(const float4*)(b1 + 16 + lq * 4);

  // per-lane pixel offsets for conv1 im2col frags
  const int kk0 = 2 * lq, kk1 = 2 * lq + 1;
  const int off0 = ((kk0 / 3) * 64 + (kk0 - 3 * (kk0 / 3))) * 4;
  const int off1 = ((kk1 / 3) * 64 + (kk1 - 3 * (kk1 / 3))) * 4;
  const int off8 = (2 * 64 + 2) * 4;  // kk=8 pixel
  __syncthreads();

  // ===== conv1: 18 pos-frags over 8 waves, K=64, C cols = pos =============
#pragma unroll
  for (int f = 0; f < 3; ++f) {
    const int mf = wid + 8 * f;
    if (mf >= 18) break;
    const int pin = mf * 16 + lrow;
    const int pv = (pin < 279) ? pin : 278;
    const int ly = pv / 31, lx = pv - 31 * ly;
    const _Float16* pb = img_s + ((2 * ly) * 64 + 2 * lx) * 4;
    uint2 p0 = *(const uint2*)(pb + off0);
    uint2 p1 = *(const uint2*)(pb + off1);
    uint2 p8 = *(const uint2*)(pb + off8);
    uint4 u0;
    u0.x = p0.x; u0.y = p0.y; u0.z = p1.x; u0.w = p1.y;
    uint4 u1;
    u1.x = (lq == 0) ? p8.x : 0u;
    u1.y = (lq == 0) ? p8.y : 0u;
    u1.z = 0u; u1.w = 0u;
    v8h a0 = __builtin_bit_cast(v8h, u0);
    v8h a1 = __builtin_bit_cast(v8h, u1);
    v4f ac0 = __builtin_bit_cast(v4f, b1q0);
    v4f ac1 = __builtin_bit_cast(v4f, b1q1);
    ac0 = __builtin_amdgcn_mfma_f32_16x16x32_f16(bw1[0][0], a0, ac0, 0, 0, 0);
    ac0 = __builtin_amdgcn_mfma_f32_16x16x32_f16(bw1[0][1], a1, ac0, 0, 0, 0);
    ac1 = __builtin_amdgcn_mfma_f32_16x16x32_f16(bw1[1][0], a0, ac1, 0, 0, 0);
    ac1 = __builtin_amdgcn_mfma_f32_16x16x32_f16(bw1[1][1], a1, ac1, 0, 0, 0);
    if (pin < nvalid) {
      char* base = c1_s + ((pin & 1) * 144 + (pin >> 1)) * 64;
      const int sw = (pin >> 2) & 3;  // 8-row period -> 2-way banks
      uint2 u;
      u.x = packrelu(ac0[0], ac0[1]);
      u.y = packrelu(ac0[2], ac0[3]);
      *(uint2*)(base + ((((lq >> 1) ^ sw) << 4) + (lq & 1) * 8)) = u;
      u.x = packrelu(ac1[0], ac1[1]);
      u.y = packrelu(ac1[2], ac1[3]);
      *(uint2*)(base + ((((2 + (lq >> 1)) ^ sw) << 4) + (lq & 1) * 8)) = u;
    }
  }
  __syncthreads();

  // ===== conv2: wave -> m-frags {2mh, 2mh+1}, nf column in regs; K=288 ====
  int abase[2];
#pragma unroll
  for (int i = 0; i < 2; ++i) {
    int pos = (2 * mh + i) * 16 + lrow;
    int pv2 = (pos < npos) ? pos : 0;
    int oy = pv2 / 15, ox = pv2 - 15 * oy;
    abase[i] = (2 * oy) * 31 + 2 * ox;
  }
  v4f acc[2];
  acc[0] = (v4f){b2v, b2v, b2v, b2v};
  acc[1] = acc[0];
#pragma unroll
  for (int kk = 0; kk < 9; ++kk) {
    const int dd = (kk / 3) * 31 + (kk - 3 * (kk / 3));
#pragma unroll
    for (int i = 0; i < 2; ++i) {
      const int pin = abase[i] + dd;
      const int sw = (pin >> 2) & 3;
      const char* base = c1_s + ((pin & 1) * 144 + (pin >> 1)) * 64;
      v8h af = *(const v8h*)(base + ((lq ^ sw) << 4));
      acc[i] =
          __builtin_amdgcn_mfma_f32_16x16x32_f16(af, wb[kk], acc[i], 0, 0, 0);
    }
  }
  __syncthreads();  // img_s reads done; overlay out_s [pos][oc]
  {
#pragma unroll
    for (int i = 0; i < 2; ++i) {
      int oc = nf * 16 + lrow;
#pragma unroll
      for (int qq = 0; qq < 4; ++qq) {
        int p = (2 * mh + i) * 16 + lq * 4 + qq;
        out_s[p * 64 + (oc ^ ((p & 3) << 4))] = hrelu(acc[i][qq]);
      }
    }
  }
  __syncthreads();
  // feat write: dense p-major chunk [basep..basep+npos)x64oc, fully coalesced
  {
    uint2* fr2 = (uint2*)fr + 16 * (60 * qh);
    const int nj = npos * 16;
    for (int j = tid; j < nj; j += 512) {
      int p = j >> 4, slot = j & 15;
      uint2 v = *(const uint2*)(out_s + p * 64 + ((slot << 2) ^ ((p & 3) << 4)));
      fr2[j] = v;
    }
  }
}

// ---------------------------------------------------------------------------
// K2: gx partials = feat @ Bw^T  (MFMA f16; BM=64, BN=192 full, split-K=8)
// ---------------------------------------------------------------------------
__global__ __launch_bounds__(256, 2) void gemm_kernel(
    const _Float16* __restrict__ feat, const _Float16* __restrict__ Bw,
    float* __restrict__ gxp, int rowBase, int mt) {
  __shared__ __align__(16) _Float16 As[2][64 * 64];
  __shared__ __align__(16) _Float16 Bs[2][192 * 64];
  const int tid = threadIdx.x;
  const int w = tid >> 6, lane = tid & 63;
  const int lrow = lane & 15, lq = lane >> 4;

  // bijective xcd-contiguous swizzle (m204)
  const int nwg = mt * SPLITK;
  const int q = nwg >> 3, r = nwg & 7;
  const int xcd = blockIdx.x & 7, pos = blockIdx.x >> 3;
  const int wg = (xcd < r ? xcd * (q + 1) : r * (q + 1) + (xcd - r) * q) + pos;
  const int sk = wg / mt, m = wg - sk * mt;
  const int bm = m * 64;
  const int ks0 = (sk * 226) / SPLITK, ks1 = ((sk + 1) * 226) / SPLITK;

  int rowA[2], kcA[2], offA[2], rowB[6], kcB[6], offB[6];
#pragma unroll
  for (int i = 0; i < 2; ++i) {
    int s = w * 128 + i * 64 + lane;
    rowA[i] = s >> 3;
    kcA[i] = s & 7;
    offA[i] = rowA[i] * 128 + ((kcA[i] ^ (rowA[i] & 7)) << 4);
  }
#pragma unroll
  for (int i = 0; i < 6; ++i) {
    int s = w * 384 + i * 64 + lane;
    rowB[i] = s >> 3;
    kcB[i] = s & 7;
    offB[i] = rowB[i] * 128 + ((kcB[i] ^ (rowB[i] & 7)) << 4);
  }

  uint4 ta[2], tb[6];
  {
    int kb = ks0 * 64;
#pragma unroll
    for (int i = 0; i < 2; ++i)
      ta[i] = *(const uint4*)(feat + (size_t)(bm + rowA[i]) * FEAT_LD + kb +
                              kcA[i] * 8);
#pragma unroll
    for (int i = 0; i < 6; ++i)
      tb[i] = *(const uint4*)(Bw + (size_t)rowB[i] * FEAT_LD + kb + kcB[i] * 8);
#pragma unroll
    for (int i = 0; i < 2; ++i) *(uint4*)((char*)As[0] + offA[i]) = ta[i];
#pragma unroll
    for (int i = 0; i < 6; ++i) *(uint4*)((char*)Bs[0] + offB[i]) = tb[i];
  }
  __syncthreads();

  v4f acc[4][3] = {};
  for (int ks = ks0; ks < ks1; ++ks) {
    const int cur = (ks - ks0) & 1;
    const bool more = (ks + 1 < ks1);
    if (more) {
      int kb = (ks + 1) * 64;
#pragma unroll
      for (int i = 0; i < 2; ++i)
        ta[i] = *(const uint4*)(feat + (size_t)(bm + rowA[i]) * FEAT_LD + kb +
                                kcA[i] * 8);
#pragma unroll
      for (int i = 0; i < 6; ++i)
        tb[i] =
            *(const uint4*)(Bw + (size_t)rowB[i] * FEAT_LD + kb + kcB[i] * 8);
    }
    const char* Ab = (const char*)As[cur];
    const char* Bb = (const char*)Bs[cur];
#pragma unroll
    for (int ksub = 0; ksub < 2; ++ksub) {
      int s0 = ksub * 4 + lq;
      v8h afr[4];
#pragma unroll
      for (int mf = 0; mf < 4; ++mf) {
        int row = mf * 16 + lrow;
        afr[mf] = *(const v8h*)(Ab + row * 128 + ((s0 ^ (row & 7)) << 4));
      }
#pragma unroll
      for (int nfi = 0; nfi < 3; ++nfi) {
        int col = (w * 3 + nfi) * 16 + lrow;
        v8h bfr = *(const v8h*)(Bb + col * 128 + ((s0 ^ (col & 7)) << 4));
#pragma unroll
        for (int mf = 0; mf < 4; ++mf)
          acc[mf][nfi] = __builtin_amdgcn_mfma_f32_16x16x32_f16(
              afr[mf], bfr, acc[mf][nfi], 0, 0, 0);
      }
    }
    if (more) {
      char* An = (char*)As[cur ^ 1];
      char* Bn = (char*)Bs[cur ^ 1];
#pragma unroll
      for (int i = 0; i < 2; ++i) *(uint4*)(An + offA[i]) = ta[i];
#pragma unroll
      for (int i = 0; i < 6; ++i) *(uint4*)(Bn + offB[i]) = tb[i];
    }
    __syncthreads();
  }
  const size_t obase = (size_t)sk * T_STEPS;
#pragma unroll
  for (int mf = 0; mf < 4; ++mf) {
#pragma unroll
    for (int nfi = 0; nfi < 3; ++nfi) {
      int col = (w * 3 + nfi) * 16 + lrow;
#pragma unroll
      for (int qq = 0; qq < 4; ++qq) {
        int rowm = bm + mf * 16 + lq * 4 + qq;
        gxp[(obase + rowBase + rowm) * 192 + col] = acc[mf][nfi][qq];
      }
    }
  }
}

// ---------------------------------------------------------------------------
// K2b: gx = sum_k gxp[k] + b_ih
// ---------------------------------------------------------------------------
__global__ __launch_bounds__(256) void reduce_gx(const float* __restrict__ gxp,
                                                 const float* __restrict__ b_ih,
                                                 float* __restrict__ gx) {
  int t = blockIdx.x * 256 + threadIdx.x;
  if (t >= T_STEPS * 192) return;
  int col = t - (t / 192) * 192;
  float s = b_ih[col];
#pragma unroll
  for (int k = 0; k < SPLITK; ++k) s += gxp[(size_t)k * T_STEPS * 192 + t];
  gx[t] = s;
}

// ---------------------------------------------------------------------------
// K3: chunked-parallel GRU scan. C=8, W=152 -> 512 blocks (2/CU), <=160
// steps. rho^152 <= 4.1e-4 @ rho=.95.
// ---------------------------------------------------------------------------
__global__ __launch_bounds__(192) void scan_kernel(
    const float* __restrict__ gx, const float* __restrict__ w_hh,
    const float* __restrict__ b_hh, float* __restrict__ hs, int C, int W) {
  __shared__ __align__(16) float h_s[64];
  __shared__ float r_s[64], z_s[64];
  const int tid = threadIdx.x;
  const int g = tid >> 6, j = tid & 63;
  const int b = blockIdx.x;
  const int tstore = b * C;
  const int t0 = max(0, tstore - W);
  const int t1 = tstore + C;

  float w[64];
#pragma unroll
  for (int k4 = 0; k4 < 16; ++k4) {
    float4 v = *(const float4*)(w_hh + tid * 64 + k4 * 4);
    w[4 * k4 + 0] = v.x;
    w[4 * k4 + 1] = v.y;
    w[4 * k4 + 2] = v.z;
    w[4 * k4 + 3] = v.w;
  }
  const float bh = b_hh[tid];
  if (tid < 64) h_s[tid] = 0.f;
  __syncthreads();

  float gxv = gx[(size_t)t0 * 192 + tid];
  for (int t = t0; t < t1; ++t) {
    int tn = (t + 1 < T_STEPS) ? t + 1 : T_STEPS - 1;
    float gxn = gx[(size_t)tn * 192 + tid];
    float gacc0 = bh, gacc1 = 0.f, gacc2 = 0.f, gacc3 = 0.f;
#pragma unroll
    for (int k4 = 0; k4 < 4; ++k4) {
      float4 hA = *(const float4*)(h_s + 0 + k4 * 4);
      float4 hB = *(const float4*)(h_s + 16 + k4 * 4);
      float4 hC = *(const float4*)(h_s + 32 + k4 * 4);
      float4 hD = *(const float4*)(h_s + 48 + k4 * 4);
      gacc0 = fmaf(w[0 + 4 * k4], hA.x, gacc0);
      gacc0 = fmaf(w[1 + 4 * k4], hA.y, gacc0);
      gacc0 = fmaf(w[2 + 4 * k4], hA.z, gacc0);
      gacc0 = fmaf(w[3 + 4 * k4], hA.w, gacc0);
      gacc1 = fmaf(w[16 + 4 * k4], hB.x, gacc1);
      gacc1 = fmaf(w[17 + 4 * k4], hB.y, gacc1);
      gacc1 = fmaf(w[18 + 4 * k4], hB.z, gacc1);
      gacc1 = fmaf(w[19 + 4 * k4], hB.w, gacc1);
      gacc2 = fmaf(w[32 + 4 * k4], hC.x, gacc2);
      gacc2 = fmaf(w[33 + 4 * k4], hC.y, gacc2);
      gacc2 = fmaf(w[34 + 4 * k4], hC.z, gacc2);
      gacc2 = fmaf(w[35 + 4 * k4], hC.w, gacc2);
      gacc3 = fmaf(w[48 + 4 * k4], hD.x, gacc3);
      gacc3 = fmaf(w[49 + 4 * k4], hD.y, gacc3);
      gacc3 = fmaf(w[50 + 4 * k4], hD.z, gacc3);
      gacc3 = fmaf(w[51 + 4 * k4], hD.w, gacc3);
    }
    float gh = (gacc0 + gacc1) + (gacc2 + gacc3);
    if (g == 0)
      r_s[j] = 1.f / (1.f + __expf(-(gxv + gh)));
    else if (g == 1)
      z_s[j] = 1.f / (1.f + __expf(-(gxv + gh)));
    __syncthreads();
    if (g == 2) {
      float r = r_s[j], z = z_s[j];
      float x = gxv + r * gh;
      float x2 = fminf(fmaxf(2.f * x, -30.f), 30.f);
      float e = __expf(x2);
      float n = (e - 1.f) / (e + 1.f);
      float hn = (1.f - z) * n + z * h_s[j];
      h_s[j] = hn;
      if (t >= tstore) hs[(size_t)t * 64 + j] = hn;
    }
    __syncthreads();
    gxv = gxn;
  }
}

// ---------------------------------------------------------------------------
// K4: actor/critic heads + softmax. Thread per timestep.
// ---------------------------------------------------------------------------
__global__ __launch_bounds__(256) void head_kernel(
    const float* __restrict__ hs, const float* __restrict__ aw,
    const float* __restrict__ ab, const float* __restrict__ cw,
    const float* __restrict__ cb, float* __restrict__ out) {
  int t = blockIdx.x * 256 + threadIdx.x;
  if (t >= T_STEPS) return;
  float h[64];
#pragma unroll
  for (int i = 0; i < 16; ++i) {
    float4 v = *(const float4*)(hs + (size_t)t * 64 + 4 * i);
    h[4 * i + 0] = v.x;
    h[4 * i + 1] = v.y;
    h[4 * i + 2] = v.z;
    h[4 * i + 3] = v.w;
  }
  float lg[7];
#pragma unroll
  for (int o = 0; o < 7; ++o) {
    float a = ab[o];
#pragma unroll
    for (int jj = 0; jj < 64; ++jj) a = fmaf(aw[o * 64 + jj], h[jj], a);
    lg[o] = a;
  }
  float v = cb[0];
#pragma unroll
  for (int jj = 0; jj < 64; ++jj) v = fmaf(cw[jj], h[jj], v);
  float m = lg[0];
#pragma unroll
  for (int o = 1; o < 7; ++o) m = fmaxf(m, lg[o]);
  float e[7], s = 0.f;
#pragma unroll
  for (int o = 0; o < 7; ++o) {
    e[o] = __expf(lg[o] - m);
    s += e[o];
  }
  float inv = 1.f / s;
#pragma unroll
  for (int o = 0; o < 7; ++o) out[(size_t)t * 7 + o] = e[o] * inv;
  out[(size_t)T_STEPS * 7 + t] = v;
}

// ---------------------------------------------------------------------------
extern "C" void kernel_launch(void* const* d_in, const int* in_sizes, int n_in,
                              void* d_out, int out_size, void* d_ws,
                              size_t ws_size, hipStream_t stream) {
  const float* image = (const float*)d_in[0];
  const int* dir = (const int*)d_in[1];
  const float* w1 = (const float*)d_in[2];
  const float* b1 = (const float*)d_in[3];
  const float* w2 = (const float*)d_in[4];
  const float* b2 = (const float*)d_in[5];
  const float* emb = (const float*)d_in[6];
  const float* w_ih = (const float*)d_in[7];
  const float* b_ih = (const float*)d_in[8];
  const float* w_hh = (const float*)d_in[9];
  const float* b_hh = (const float*)d_in[10];
  const float* aw = (const float*)d_in[11];
  const float* ab = (const float*)d_in[12];
  const float* cw = (const float*)d_in[13];
  const float* cb = (const float*)d_in[14];
  float* out = (float*)d_out;

  const size_t bp1Bytes = 4096;        // conv1 W frags
  const size_t bpackBytes = 18432 * 2; // conv2 B frags
  const size_t bBytes = (size_t)192 * FEAT_LD * 2;
  const size_t gxpBytes = (size_t)SPLITK * T_STEPS * 192 * 4;
  const size_t gxBytes = (size_t)T_STEPS * 192 * 4;
  const size_t hsBytes = (size_t)T_STEPS * 64 * 4;
  const size_t fixed =
      bp1Bytes + bpackBytes + bBytes + gxpBytes + gxBytes + hsBytes;
  int CH = 4096;
  while (CH > 256 && fixed + (size_t)CH * FEAT_LD * 2 > ws_size) CH >>= 1;

  char* p = (char*)d_ws;
  _Float16* bpack1 = (_Float16*)p;
  p += bp1Bytes;
  _Float16* bpack = (_Float16*)p;
  p += bpackBytes;
  _Float16* Bw = (_Float16*)p;
  p += bBytes;
  float* gxp = (float*)p;
  p += gxpBytes;
  float* gx = (float*)p;
  p += gxBytes;
  float* hs = (float*)p;
  p += hsBytes;
  _Float16* featBuf = (_Float16*)p;

  prep_conv<<<72, 256, 0, stream>>>(w1, w2, bpack1, bpack);
  prep_b<<<(192 * FEAT_LD + 255) / 256, 256, 0, stream>>>(w_ih, Bw);
  for (int c = 0; c < T_STEPS; c += CH) {
    conv_kernel<<<dim3(4, CH), 512, 0, stream>>>(image, dir, bpack1, b1, bpack,
                                                 b2, emb, featBuf, c);
    gemm_kernel<<<(CH / 64) * SPLITK, 256, 0, stream>>>(featBuf, Bw, gxp, c,
                                                        CH / 64);
  }
  reduce_gx<<<(T_STEPS * 192 + 255) / 256, 256, 0, stream>>>(gxp, b_ih, gx);
  scan_kernel<<<512, 192, 0, stream>>>(gx, w_hh, b_hh, hs, 8, 152);
  head_kernel<<<(T_STEPS + 255) / 256, 256, 0, stream>>>(hs, aw, ab, cw, cb,
                                                         out);
}